// Round 4
// baseline (247.022 us; speedup 1.0000x reference)
//
#include <hip/hip_runtime.h>
#include <math.h>

// 31x31 depthwise Gaussian (sigma=3) == separable 25-tap Gaussian applied
// twice (outer 3 taps are exactly zero). Reflection effectively at radius 12.
//
// R4: one LDS round-trip only (mid), ONE barrier.
//  - weights via uniform scalar loads -> SGPRs (no k1s LDS, no init barrier)
//  - H pass: global -> reg window (8 aligned float4) -> 25-tap row conv ->
//    float4x2 write to mid. MSTRIDE=68 (==4 mod 32): float4-granular start
//    banks spread by 4 -> balanced for any b32/b64/b128 merge (R3's 65 gave
//    1.9e7 conflict cycles on merged wide writes).
//  - V pass: float4-wide sliding window: thread = 4 cols x 4 rows,
//    28 ds_read_b128 feed 400 FMAs, 4 global_store_dwordx4.
// No min-waves launch_bounds (R2: (256,6) -> forced spill, 2.6 GB scratch).

#define IW 512
#define IH 512
#define RAD 12
#define TW 64
#define TH 64
#define MROWS (TH + 2*RAD)      // 88 mid rows
#define MSTRIDE 68              // fp32; 68 % 32 == 4 -> conflict-free wide ops
#define NHTASK (MROWS * 8)      // 704 horizontal tasks (88 rows x 8 groups)

#define KW(t) ((t) <= 12 ? kk[(t)] : kk[24 - (t)])

__global__ __launch_bounds__(256)
void gauss_blur_sep4_kernel(const float* __restrict__ x,
                            const float* __restrict__ wgt,
                            float* __restrict__ out)
{
    __shared__ float mid[MROWS * MSTRIDE];   // 23936 B

    const int tid = threadIdx.x;
    const int z   = blockIdx.z;
    const int ch  = z % 3;

    // 1D kernel from 2D weight (uniform -> scalar loads into SGPRs):
    // w2d = outer(f,f); k1[t] = w2d[15][3+t] / sqrt(w2d[15][15]); symmetric.
    const float* __restrict__ wp = wgt + ch * 961 + 15 * 31;
    const float inv = rsqrtf(wp[15]);
    float kk[13];
#pragma unroll
    for (int t = 0; t < 13; ++t) kk[t] = wp[3 + t] * inv;

    const int r0g = blockIdx.y * TH;
    const int c0g = blockIdx.x * TW;
    const float* __restrict__ src = x + (size_t)z * (IW * IH);

    // ---------- H pass: global -> regs -> mid (LDS) ----------
    // task: row m = task>>3 (0..87 -> global row r0g+m-12, reflected),
    //       group g = task&7 (8 outputs at cols c0g+8g .. +7).
    // Window: 32 floats from col c0g+8g-12 (float4-aligned by construction).
#pragma unroll
    for (int s = 0; s < 3; ++s) {
        const int task = tid + s * 256;
        if (s < 2 || task < NHTASK) {      // slot 2: waves 0-2 only (uniform)
            const int g = task & 7, m = task >> 3;
            int gr = r0g + m - RAD;
            gr = gr < 0 ? -gr : (gr >= IH ? 2 * IH - 2 - gr : gr);
            const float* __restrict__ srow = src + (size_t)gr * IW;
            const int wc0 = c0g + 8 * g - RAD;

            float v[32];
            if (wc0 >= 0 && wc0 + 32 <= IW) {
                const float4* __restrict__ p = (const float4*)(srow + wc0);
#pragma unroll
                for (int q = 0; q < 8; ++q) {
                    float4 f = p[q];
                    v[4*q+0] = f.x; v[4*q+1] = f.y; v[4*q+2] = f.z; v[4*q+3] = f.w;
                }
            } else {                        // edge blocks only (bx==0 / bx==7)
#pragma unroll
                for (int j = 0; j < 32; ++j) {
                    int gc = wc0 + j;
                    gc = gc < 0 ? -gc : (gc >= IW ? 2 * IW - 2 - gc : gc);
                    v[j] = srow[gc];
                }
            }

            float r[8];
#pragma unroll
            for (int o = 0; o < 8; ++o) {
                float acc = v[o + 12] * kk[12];
#pragma unroll
                for (int t = 0; t < 12; ++t)
                    acc = fmaf(v[o + t] + v[o + 24 - t], kk[t], acc);
                r[o] = acc;
            }
            float* mw = &mid[m * MSTRIDE + 8 * g];
            *(float4*)(mw)     = make_float4(r[0], r[1], r[2], r[3]);
            *(float4*)(mw + 4) = make_float4(r[4], r[5], r[6], r[7]);
        }
    }
    __syncthreads();

    // ---------- V pass: float4-wide sliding window, mid -> out ----------
    // thread: cols 4*cg..4*cg+3 (cg = tid&15), rows rb..rb+3 (rb = (tid>>4)*4).
    // 28 ds_read_b128 feed 400 FMAs -> 16 outputs -> 4 dwordx4 stores.
    const int cg = tid & 15;
    const int rb = (tid >> 4) * 4;

    float4 acc[4];
#pragma unroll
    for (int o = 0; o < 4; ++o) acc[o] = make_float4(0.f, 0.f, 0.f, 0.f);

#pragma unroll
    for (int m2 = 0; m2 < 28; ++m2) {
        const float4 vr = *(const float4*)(&mid[(rb + m2) * MSTRIDE + 4 * cg]);
#pragma unroll
        for (int o = 0; o < 4; ++o) {
            const int t = m2 - o;
            if (t >= 0 && t < 25) {
                const float w = KW(t);
                acc[o].x = fmaf(vr.x, w, acc[o].x);
                acc[o].y = fmaf(vr.y, w, acc[o].y);
                acc[o].z = fmaf(vr.z, w, acc[o].z);
                acc[o].w = fmaf(vr.w, w, acc[o].w);
            }
        }
    }

    float* __restrict__ dst = out + (size_t)z * (IW * IH)
                            + (size_t)(r0g + rb) * IW + c0g + 4 * cg;
#pragma unroll
    for (int o = 0; o < 4; ++o) {
        *(float4*)(dst + (size_t)o * IW) = acc[o];
    }
}

extern "C" void kernel_launch(void* const* d_in, const int* in_sizes, int n_in,
                              void* d_out, int out_size, void* d_ws, size_t ws_size,
                              hipStream_t stream)
{
    const float* x   = (const float*)d_in[0];
    const float* wgt = (const float*)d_in[1];
    float* out = (float*)d_out;

    dim3 grid(IW / TW, IH / TH, 96);   // 8 x 8 x 96 = 6144 blocks
    gauss_blur_sep4_kernel<<<grid, dim3(256), 0, stream>>>(x, wgt, out);
}